// Round 15
// baseline (108.591 us; speedup 1.0000x reference)
//
#include <hip/hip_runtime.h>
#include <math.h>

#define BB 2
#define NN 384
#define DD 256
#define HH 8
#define RN (BB * NN)   // 768
#define INV_SQRT_HD 0.17677669529663687f   // 1/sqrt(32)
#define LOG2E 1.4426950408889634f
#define NLN2 -0.6931471805599453f
#define QSCALE (INV_SQRT_HD * LOG2E)

#define W2_ST 264   // bf16 stride, rb_w2 rows in LDS
#define EB_ST 392   // bf16 stride, staged e rows (196 words; %32=4 -> 2-way free)
#define TB_ST 264   // bf16 stride, Tb rows

typedef float f32x4 __attribute__((ext_vector_type(4)));
typedef __bf16 bf16x8 __attribute__((ext_vector_type(8)));
typedef __bf16 bf16x4 __attribute__((ext_vector_type(4)));

__device__ __forceinline__ f32x4 mfma16(bf16x8 a, bf16x8 b, f32x4 c) {
    return __builtin_amdgcn_mfma_f32_16x16x32_bf16(a, b, c, 0, 0, 0);
}

// d = av' - ap' (primes pre-scaled by log2e) = -x*log2e.
// returns -log2e*silu(x); folds: k2a w2bf=-rb_w2; k2b Tb *= -ln2.
__device__ __forceinline__ float hidp(float d) {
    float e = __builtin_amdgcn_exp2f(d);
    return d * __builtin_amdgcn_rcpf(1.0f + e);
}
__device__ __forceinline__ bf16x8 hid8(bf16x8 av, float4 a0, float4 a1) {
    bf16x8 r;
    r[0] = (__bf16)hidp((float)av[0] - a0.x);
    r[1] = (__bf16)hidp((float)av[1] - a0.y);
    r[2] = (__bf16)hidp((float)av[2] - a0.z);
    r[3] = (__bf16)hidp((float)av[3] - a0.w);
    r[4] = (__bf16)hidp((float)av[4] - a1.x);
    r[5] = (__bf16)hidp((float)av[5] - a1.y);
    r[6] = (__bf16)hidp((float)av[6] - a1.z);
    r[7] = (__bf16)hidp((float)av[7] - a1.w);
    return r;
}
__device__ __forceinline__ bf16x8 hid8s(bf16x8 av, float a) {
    bf16x8 r;
#pragma unroll
    for (int q = 0; q < 8; ++q) r[q] = (__bf16)hidp((float)av[q] - a);
    return r;
}
__device__ __forceinline__ bf16x8 pack8(float4 a, float4 b) {
    bf16x8 r;
    r[0] = (__bf16)a.x; r[1] = (__bf16)a.y; r[2] = (__bf16)a.z; r[3] = (__bf16)a.w;
    r[4] = (__bf16)b.x; r[5] = (__bf16)b.y; r[6] = (__bf16)b.z; r[7] = (__bf16)b.w;
    return r;
}
__device__ __forceinline__ float selv(f32x4 v, int r) {
    return (r == 0) ? v[0] : (r == 1) ? v[1] : (r == 2) ? v[2] : v[3];
}

// ---------------- Kernel 1: fused prep (unchanged from r14) ----------------
__global__ __launch_bounds__(256) void prep_kernel(
    const float* __restrict__ x, const float* __restrict__ coords,
    const float* __restrict__ qkv_w, const float* __restrict__ qkv_b,
    const float* __restrict__ rb_w1, const float* __restrict__ rv_w1,
    const float* __restrict__ rb_w2,
    float* __restrict__ qb, __bf16* __restrict__ kbbf, __bf16* __restrict__ vT,
    __bf16* __restrict__ Arb, __bf16* __restrict__ ArvT, __bf16* __restrict__ Arv,
    __bf16* __restrict__ w2neg)
{
    int bid = blockIdx.x, tid = threadIdx.x;
    if (bid >= 1344) {
        int idx = tid * 8;
        float4 wa = *(const float4*)(rb_w2 + idx);
        float4 wb = *(const float4*)(rb_w2 + idx + 4);
        float4 na = make_float4(-wa.x, -wa.y, -wa.z, -wa.w);
        float4 nb = make_float4(-wb.x, -wb.y, -wb.z, -wb.w);
        *(bf16x8*)(w2neg + idx) = pack8(na, nb);
        return;
    }
    if (bid >= 576) {
        int r = bid - 576, c = tid;
        float cx = coords[r * 3 + 0], cy = coords[r * 3 + 1], cz = coords[r * 3 + 2];
        float ab = (cx * rb_w1[c * 3] + cy * rb_w1[c * 3 + 1] + cz * rb_w1[c * 3 + 2]) * LOG2E;
        float av = (cx * rv_w1[c * 3] + cy * rv_w1[c * 3 + 1] + cz * rv_w1[c * 3 + 2]) * LOG2E;
        Arb[r * DD + c] = (__bf16)ab;
        ArvT[c * RN + r] = (__bf16)av;
        Arv[r * DD + c] = (__bf16)av;
        return;
    }
    int mt = bid % 48, nb = bid / 48;
    int w = tid >> 6, l = tid & 63, lr = l & 15, lg = l >> 4;
    int m0 = mt * 16, n0 = nb * 64 + w * 16;
    const float* xr = x + (size_t)(m0 + lr) * DD;
    const float* wr = qkv_w + (size_t)(n0 + lr) * DD;
    f32x4 acc = {0.f, 0.f, 0.f, 0.f};
#pragma unroll
    for (int ks = 0; ks < 8; ++ks) {
        int c0 = ks * 32 + lg * 8;
        float4 xa = *(const float4*)(xr + c0);
        float4 xb = *(const float4*)(xr + c0 + 4);
        float4 wa = *(const float4*)(wr + c0);
        float4 wb = *(const float4*)(wr + c0 + 4);
        acc = mfma16(pack8(xa, xb), pack8(wa, wb), acc);
    }
    int col = n0 + lr;
    float bo = qkv_b[col];
    int part = col >> 8, o = col & 255;
#pragma unroll
    for (int r = 0; r < 4; ++r) {
        int m = m0 + lg * 4 + r;
        float v = acc[r] + bo;
        if (part == 0) {
            qb[(size_t)m * DD + o] = v * QSCALE;
        } else if (part == 1) {
            kbbf[(size_t)m * DD + o] = (__bf16)v;
        } else {
            int b = (m >= NN) ? 1 : 0;
            int n = m - b * NN;
            vT[(size_t)b * DD * NN + (size_t)o * NN + n] = (__bf16)v;
        }
    }
}

// ---------------- Kernel 2a: scores + e, gi-QUAD per block ----------------
// grid = 384 (192 quads x 2 j-halves), 256 thr. ar/k streams shared across 4 queries.
__global__ __launch_bounds__(256, 4) void k2a_kernel(
    const float* __restrict__ rb_b1, const __bf16* __restrict__ w2neg,
    const float* __restrict__ rb_b2,
    const float* __restrict__ qb, const __bf16* __restrict__ kbbf,
    const __bf16* __restrict__ Arb,
    __bf16* __restrict__ eG, float* __restrict__ Zpart)
{
    __shared__ __align__(16) __bf16 qsbf[4][DD];
    __shared__ __align__(16) float Apr[4][DD];
    __shared__ __align__(16) __bf16 w2bf[HH * W2_ST];
    __shared__ float redsm[4][4][HH];

    int tid = threadIdx.x;
    int bid = blockIdx.x;
    int gq = bid >> 1, half = bid & 1;
    int gi0 = gq * 4;
    int b = (gq >= 96) ? 1 : 0;

    float b1l = rb_b1[tid] * LOG2E;
#pragma unroll
    for (int g = 0; g < 4; ++g) {
        qsbf[g][tid] = (__bf16)qb[(size_t)(gi0 + g) * DD + tid];
        Apr[g][tid] = (float)Arb[(size_t)(gi0 + g) * DD + tid] + b1l;
    }
    {
        int idx = tid * 8;
        *(bf16x8*)&w2bf[(idx >> 8) * W2_ST + (idx & 255)] =
            *(const bf16x8*)(w2neg + idx);
    }
    __syncthreads();

    int l = tid & 63, wv = tid >> 6;
    int lr = l & 15, lg = l >> 4;
    float rb2l = rb_b2[lr & 7] * LOG2E;

    int jb0 = half * 192 + wv * 16;
    const __bf16* arbB = Arb + (size_t)b * NN * DD;
    const __bf16* kbB  = kbbf + (size_t)b * NN * DD;
    const __bf16* ar0 = arbB + (size_t)(jb0 + lr) * DD;
    const __bf16* ar1 = ar0 + (size_t)64 * DD;
    const __bf16* ar2 = ar0 + (size_t)128 * DD;
    const __bf16* kr0 = kbB + (size_t)(jb0 + lr) * DD;
    const __bf16* kr1 = kr0 + (size_t)64 * DD;
    const __bf16* kr2 = kr0 + (size_t)128 * DD;
    const __bf16* wfp = &w2bf[(lr & 7) * W2_ST];

    bf16x8 qfr[4];
#pragma unroll
    for (int g = 0; g < 4; ++g)
        qfr[g] = *(const bf16x8*)&qsbf[g][(lr & 7) * 32 + lg * 8];
    bf16x8 zero8;
#pragma unroll
    for (int e = 0; e < 8; ++e) zero8[e] = (__bf16)0.f;

    f32x4 acc[4][3];
#pragma unroll
    for (int g = 0; g < 4; ++g)
#pragma unroll
        for (int t = 0; t < 3; ++t)
            acc[g][t] = (f32x4){0.f, 0.f, 0.f, 0.f};

#pragma unroll
    for (int ks = 0; ks < 8; ++ks) {
        int c0 = ks * 32 + lg * 8;
        bf16x8 v0 = *(const bf16x8*)(ar0 + c0);
        bf16x8 v1 = *(const bf16x8*)(ar1 + c0);
        bf16x8 v2 = *(const bf16x8*)(ar2 + c0);
        bf16x8 k0 = *(const bf16x8*)(kr0 + c0);
        bf16x8 k1 = *(const bf16x8*)(kr1 + c0);
        bf16x8 k2 = *(const bf16x8*)(kr2 + c0);
        bf16x8 wf = *(const bf16x8*)(wfp + c0);
#pragma unroll
        for (int g = 0; g < 4; ++g) {
            float4 pa = *(const float4*)&Apr[g][c0];
            float4 pb = *(const float4*)&Apr[g][c0 + 4];
            bf16x8 qf = (lr == ks) ? qfr[g] : zero8;
            acc[g][0] = mfma16(hid8(v0, pa, pb), wf, acc[g][0]);
            acc[g][1] = mfma16(hid8(v1, pa, pb), wf, acc[g][1]);
            acc[g][2] = mfma16(hid8(v2, pa, pb), wf, acc[g][2]);
            acc[g][0] = mfma16(k0, qf, acc[g][0]);
            acc[g][1] = mfma16(k1, qf, acc[g][1]);
            acc[g][2] = mfma16(k2, qf, acc[g][2]);
        }
    }

#pragma unroll
    for (int g = 0; g < 4; ++g) {
        float z = 0.f;
#pragma unroll
        for (int t = 0; t < 3; ++t) {
            float e0 = __builtin_amdgcn_exp2f(acc[g][t][0] + rb2l);
            float e1 = __builtin_amdgcn_exp2f(acc[g][t][1] + rb2l);
            float e2 = __builtin_amdgcn_exp2f(acc[g][t][2] + rb2l);
            float e3 = __builtin_amdgcn_exp2f(acc[g][t][3] + rb2l);
            if (lr < 8) {
                bf16x4 ev;
                ev[0] = (__bf16)e0; ev[1] = (__bf16)e1;
                ev[2] = (__bf16)e2; ev[3] = (__bf16)e3;
                *(bf16x4*)&eG[((size_t)(gi0 + g) * HH + lr) * NN + jb0 + t * 64 + lg * 4] = ev;
            }
            float zs = e0 + e1 + e2 + e3;
            zs += __shfl_xor(zs, 16);
            zs += __shfl_xor(zs, 32);
            z += zs;
        }
        if (lg == 0 && lr < 8) redsm[wv][g][lr] = z;
    }
    __syncthreads();
    if (tid < 32) {
        int g = tid >> 3, h = tid & 7;
        Zpart[((size_t)(gi0 + g) * 2 + half) * 8 + h] =
            redsm[0][g][h] + redsm[1][g][h] + redsm[2][g][h] + redsm[3][g][h];
    }
}

// ---------------- Kernel 2b: T/base, gi-QUAD, e staged in LDS (2 pair-groups) ----------------
// grid = 384 (192 quads x 2 c-halves), 256 thr, 12 K-iters. Tb in bf16.
__global__ __launch_bounds__(256, 4) void k2b_kernel(
    const float* __restrict__ rv_b1, const float* __restrict__ rv_w2,
    const __bf16* __restrict__ vT, const __bf16* __restrict__ ArvT,
    const __bf16* __restrict__ Arv, const __bf16* __restrict__ eG,
    float* __restrict__ rcpart, float* __restrict__ basef)
{
    __shared__ __align__(16) float Apv[4][DD];           // 4 KB
    __shared__ __align__(16) __bf16 Tb[4][HH * TB_ST];   // 16.9 KB
    __shared__ __align__(16) __bf16 els[32 * EB_ST];     // 25 KB

    int tid = threadIdx.x;
    int bid = blockIdx.x;
    int gq = bid >> 1, ch = bid & 1;
    int gi0 = gq * 4;
    int b = (gq >= 96) ? 1 : 0;

    float b1l = rv_b1[tid] * LOG2E;
#pragma unroll
    for (int g = 0; g < 4; ++g)
        Apv[g][tid] = (float)Arv[(size_t)(gi0 + g) * DD + tid] + b1l;
    // stage 32 e-rows (rows r = g*8+h): ef0 = rows 0-15 (gi0,gi1), ef1 = rows 16-31
    {
        const __bf16* src = eG + (size_t)(gi0 * 8) * NN;
#pragma unroll
        for (int s = 0; s < 6; ++s) {
            int idx = tid + s * 256;
            int r = idx / 48, cc = idx - r * 48;
            *(bf16x8*)&els[r * EB_ST + cc * 8] =
                *(const bf16x8*)(src + (size_t)r * NN + cc * 8);
        }
    }
    __syncthreads();

    int l = tid & 63, wv = tid >> 6;
    int lr = l & 15, lg = l >> 4;

    int c0 = ch * 128 + wv * 16 + lr;
    int c1 = c0 + 64;
    float ap[4][2];
#pragma unroll
    for (int g = 0; g < 4; ++g) {
        ap[g][0] = Apv[g][c0];
        ap[g][1] = Apv[g][c1];
    }
    const __bf16* vr0 = ArvT + (size_t)c0 * RN + b * NN;
    const __bf16* vr1 = ArvT + (size_t)c1 * RN + b * NN;
    const __bf16* tv0 = vT + (size_t)b * DD * NN + (size_t)c0 * NN;
    const __bf16* tv1 = vT + (size_t)b * DD * NN + (size_t)c1 * NN;

    f32x4 T[4][2], Bk[2][2];
#pragma unroll
    for (int g = 0; g < 4; ++g) {
        T[g][0] = (f32x4){0.f, 0.f, 0.f, 0.f};
        T[g][1] = (f32x4){0.f, 0.f, 0.f, 0.f};
    }
    Bk[0][0] = Bk[0][1] = Bk[1][0] = Bk[1][1] = (f32x4){0.f, 0.f, 0.f, 0.f};

#pragma unroll
    for (int ks = 0; ks < 12; ++ks) {
        int j0 = ks * 32 + lg * 8;
        bf16x8 ef0 = *(const bf16x8*)&els[lr * EB_ST + j0];
        bf16x8 ef1 = *(const bf16x8*)&els[(16 + lr) * EB_ST + j0];
        bf16x8 av0 = *(const bf16x8*)(vr0 + j0);
        bf16x8 av1 = *(const bf16x8*)(vr1 + j0);
        bf16x8 w0  = *(const bf16x8*)(tv0 + j0);
        bf16x8 w1  = *(const bf16x8*)(tv1 + j0);
#pragma unroll
        for (int g = 0; g < 4; ++g) {
            bf16x8 e = (g < 2) ? ef0 : ef1;
            T[g][0] = mfma16(e, hid8s(av0, ap[g][0]), T[g][0]);
            T[g][1] = mfma16(e, hid8s(av1, ap[g][1]), T[g][1]);
        }
        Bk[0][0] = mfma16(ef0, w0, Bk[0][0]);
        Bk[0][1] = mfma16(ef0, w1, Bk[0][1]);
        Bk[1][0] = mfma16(ef1, w0, Bk[1][0]);
        Bk[1][1] = mfma16(ef1, w1, Bk[1][1]);
    }

    // T extraction: even g -> D rows 0-7 (lg<2), odd g -> rows 8-15 (lg>=2). bf16, *(-ln2).
#pragma unroll
    for (int g = 0; g < 4; ++g) {
        if (!(g & 1)) {
            if (lg < 2) {
#pragma unroll
                for (int r = 0; r < 4; ++r) {
                    int h = lg * 4 + r;
                    Tb[g][h * TB_ST + c0] = (__bf16)(T[g][0][r] * NLN2);
                    Tb[g][h * TB_ST + c1] = (__bf16)(T[g][1][r] * NLN2);
                }
            }
        } else {
            if (lg >= 2) {
#pragma unroll
                for (int r = 0; r < 4; ++r) {
                    int h = (lg - 2) * 4 + r;
                    Tb[g][h * TB_ST + c0] = (__bf16)(T[g][0][r] * NLN2);
                    Tb[g][h * TB_ST + c1] = (__bf16)(T[g][1][r] * NLN2);
                }
            }
        }
    }
    // base: col c needs D row h=c>>5 (even g) / 8+h (odd g); pair-group from Bk
#pragma unroll
    for (int cs = 0; cs < 2; ++cs) {
        int c = cs ? c1 : c0;
        int h = c >> 5;
        if (lg == (h >> 2)) {
            basef[(size_t)(gi0 + 0) * DD + c] = selv(Bk[0][cs], h & 3);
            basef[(size_t)(gi0 + 2) * DD + c] = selv(Bk[1][cs], h & 3);
        }
        if (lg == 2 + (h >> 2)) {
            basef[(size_t)(gi0 + 1) * DD + c] = selv(Bk[0][cs], h & 3);
            basef[(size_t)(gi0 + 3) * DD + c] = selv(Bk[1][cs], h & 3);
        }
    }
    __syncthreads();

    // rc partials over this c-half for all 4 queries: o = tid
    {
        int o = tid, h = o >> 5;
        const float4* w2p = (const float4*)(rv_w2 + (size_t)o * DD);
#pragma unroll
        for (int g = 0; g < 4; ++g) {
            const __bf16* trow = &Tb[g][h * TB_ST];
            float a = 0.f;
#pragma unroll 4
            for (int cc = 0; cc < 32; ++cc) {
                int cidx = ch * 32 + cc;
                float4 w4 = w2p[cidx];
                bf16x4 u = *(const bf16x4*)&trow[cidx * 4];
                a += w4.x * (float)u[0] + w4.y * (float)u[1]
                   + w4.z * (float)u[2] + w4.w * (float)u[3];
            }
            rcpart[((size_t)ch * RN + gi0 + g) * DD + o] = a;
        }
    }
}

// ---------------- Kernel 2c: combine. grid = 768, 256 thr ----------------
__global__ __launch_bounds__(256) void k2c_kernel(
    const float* __restrict__ rcpart, const float* __restrict__ basef,
    const float* __restrict__ Zpart, const float* __restrict__ rv_b2,
    float* __restrict__ out)
{
    int gi = blockIdx.x, o = threadIdx.x, h = o >> 5;
    float z = Zpart[(size_t)gi * 16 + h] + Zpart[(size_t)gi * 16 + 8 + h];
    float rc = rcpart[(size_t)gi * DD + o] + rcpart[((size_t)RN + gi) * DD + o];
    out[(size_t)gi * DD + o] =
        (rc + basef[(size_t)gi * DD + o]) * __builtin_amdgcn_rcpf(z) + rv_b2[o];
}

extern "C" void kernel_launch(void* const* d_in, const int* in_sizes, int n_in,
                              void* d_out, int out_size, void* d_ws, size_t ws_size,
                              hipStream_t stream) {
    const float* x      = (const float*)d_in[0];
    const float* coords = (const float*)d_in[1];
    const float* qkv_w  = (const float*)d_in[2];
    const float* qkv_b  = (const float*)d_in[3];
    const float* rb_w1  = (const float*)d_in[4];
    const float* rb_b1  = (const float*)d_in[5];
    const float* rb_w2  = (const float*)d_in[6];
    const float* rb_b2  = (const float*)d_in[7];
    const float* rv_w1  = (const float*)d_in[8];
    const float* rv_b1  = (const float*)d_in[9];
    const float* rv_w2  = (const float*)d_in[10];
    const float* rv_b2  = (const float*)d_in[11];
    float* out = (float*)d_out;

    float* ws = (float*)d_ws;
    const int PER = RN * DD;               // 196608
    float* qb = ws;                        // PER f32
    __bf16* bfb  = (__bf16*)(ws + PER);
    __bf16* kbbf = bfb;                    // PER bf16
    __bf16* vTb  = bfb + PER;              // PER bf16
    __bf16* Arb  = bfb + 2 * PER;          // PER bf16
    __bf16* ArvT = bfb + 3 * PER;          // PER bf16
    __bf16* Arv  = bfb + 4 * PER;          // PER bf16 (row-major copy)
    __bf16* eG   = bfb + 5 * (size_t)PER;  // RN*HH*NN bf16
    float* Zpart = (float*)(eG + (size_t)RN * HH * NN);   // RN*2*HH f32
    float* basef = Zpart + (size_t)RN * 2 * HH;           // PER f32
    float* rcpart = basef + PER;                          // 2*PER f32
    __bf16* w2neg = (__bf16*)(rcpart + 2 * (size_t)PER);  // 2048 bf16

    prep_kernel<<<1345, 256, 0, stream>>>(x, coords, qkv_w, qkv_b,
                                          rb_w1, rv_w1, rb_w2,
                                          qb, kbbf, vTb, Arb, ArvT, Arv, w2neg);
    k2a_kernel<<<384, 256, 0, stream>>>(rb_b1, w2neg, rb_b2,
                                        qb, kbbf, Arb, eG, Zpart);
    k2b_kernel<<<384, 256, 0, stream>>>(rv_b1, rv_w2,
                                        vTb, ArvT, Arv, eG, rcpart, basef);
    k2c_kernel<<<RN, 256, 0, stream>>>(rcpart, basef, Zpart, rv_b2, out);
}

// Round 16
// 82.742 us; speedup vs baseline: 1.3124x; 1.3124x over previous
//
#include <hip/hip_runtime.h>
#include <math.h>

#define BB 2
#define NN 384
#define DD 256
#define HH 8
#define RN (BB * NN)   // 768
#define INV_SQRT_HD 0.17677669529663687f   // 1/sqrt(32)
#define LOG2E 1.4426950408889634f
#define NLN2 -0.6931471805599453f
#define QSCALE (INV_SQRT_HD * LOG2E)

#define W2_ST 264   // bf16 stride, rb_w2 rows in LDS
#define EB_ST 392   // bf16 stride, staged e rows (196 words; %32=4 -> 2-way free)
#define TB_ST 68    // bf16 stride, Tb rows (136B -> rows 2 banks apart)

typedef float f32x4 __attribute__((ext_vector_type(4)));
typedef __bf16 bf16x8 __attribute__((ext_vector_type(8)));
typedef __bf16 bf16x4 __attribute__((ext_vector_type(4)));

__device__ __forceinline__ f32x4 mfma16(bf16x8 a, bf16x8 b, f32x4 c) {
    return __builtin_amdgcn_mfma_f32_16x16x32_bf16(a, b, c, 0, 0, 0);
}

// d = av' - ap' (primes pre-scaled by log2e) = -x*log2e.
// returns -log2e*silu(x); folds: k2a w2bf=-rb_w2; k2b Tb *= -ln2.
__device__ __forceinline__ float hidp(float d) {
    float e = __builtin_amdgcn_exp2f(d);
    return d * __builtin_amdgcn_rcpf(1.0f + e);
}
__device__ __forceinline__ bf16x8 hid8(bf16x8 av, float4 a0, float4 a1) {
    bf16x8 r;
    r[0] = (__bf16)hidp((float)av[0] - a0.x);
    r[1] = (__bf16)hidp((float)av[1] - a0.y);
    r[2] = (__bf16)hidp((float)av[2] - a0.z);
    r[3] = (__bf16)hidp((float)av[3] - a0.w);
    r[4] = (__bf16)hidp((float)av[4] - a1.x);
    r[5] = (__bf16)hidp((float)av[5] - a1.y);
    r[6] = (__bf16)hidp((float)av[6] - a1.z);
    r[7] = (__bf16)hidp((float)av[7] - a1.w);
    return r;
}
__device__ __forceinline__ bf16x8 hid8s(bf16x8 av, float a) {
    bf16x8 r;
#pragma unroll
    for (int q = 0; q < 8; ++q) r[q] = (__bf16)hidp((float)av[q] - a);
    return r;
}
__device__ __forceinline__ bf16x8 pack8(float4 a, float4 b) {
    bf16x8 r;
    r[0] = (__bf16)a.x; r[1] = (__bf16)a.y; r[2] = (__bf16)a.z; r[3] = (__bf16)a.w;
    r[4] = (__bf16)b.x; r[5] = (__bf16)b.y; r[6] = (__bf16)b.z; r[7] = (__bf16)b.w;
    return r;
}
__device__ __forceinline__ float selv(f32x4 v, int r) {
    return (r == 0) ? v[0] : (r == 1) ? v[1] : (r == 2) ? v[2] : v[3];
}

// ---------------- Kernel 1: fused prep (unchanged, r14) ----------------
__global__ __launch_bounds__(256) void prep_kernel(
    const float* __restrict__ x, const float* __restrict__ coords,
    const float* __restrict__ qkv_w, const float* __restrict__ qkv_b,
    const float* __restrict__ rb_w1, const float* __restrict__ rv_w1,
    const float* __restrict__ rb_w2,
    float* __restrict__ qb, __bf16* __restrict__ kbbf, __bf16* __restrict__ vT,
    __bf16* __restrict__ Arb, __bf16* __restrict__ ArvT, __bf16* __restrict__ Arv,
    __bf16* __restrict__ w2neg)
{
    int bid = blockIdx.x, tid = threadIdx.x;
    if (bid >= 1344) {
        int idx = tid * 8;
        float4 wa = *(const float4*)(rb_w2 + idx);
        float4 wb = *(const float4*)(rb_w2 + idx + 4);
        float4 na = make_float4(-wa.x, -wa.y, -wa.z, -wa.w);
        float4 nb = make_float4(-wb.x, -wb.y, -wb.z, -wb.w);
        *(bf16x8*)(w2neg + idx) = pack8(na, nb);
        return;
    }
    if (bid >= 576) {
        int r = bid - 576, c = tid;
        float cx = coords[r * 3 + 0], cy = coords[r * 3 + 1], cz = coords[r * 3 + 2];
        float ab = (cx * rb_w1[c * 3] + cy * rb_w1[c * 3 + 1] + cz * rb_w1[c * 3 + 2]) * LOG2E;
        float av = (cx * rv_w1[c * 3] + cy * rv_w1[c * 3 + 1] + cz * rv_w1[c * 3 + 2]) * LOG2E;
        Arb[r * DD + c] = (__bf16)ab;
        ArvT[c * RN + r] = (__bf16)av;
        Arv[r * DD + c] = (__bf16)av;
        return;
    }
    int mt = bid % 48, nb = bid / 48;
    int w = tid >> 6, l = tid & 63, lr = l & 15, lg = l >> 4;
    int m0 = mt * 16, n0 = nb * 64 + w * 16;
    const float* xr = x + (size_t)(m0 + lr) * DD;
    const float* wr = qkv_w + (size_t)(n0 + lr) * DD;
    f32x4 acc = {0.f, 0.f, 0.f, 0.f};
#pragma unroll
    for (int ks = 0; ks < 8; ++ks) {
        int c0 = ks * 32 + lg * 8;
        float4 xa = *(const float4*)(xr + c0);
        float4 xb = *(const float4*)(xr + c0 + 4);
        float4 wa = *(const float4*)(wr + c0);
        float4 wb = *(const float4*)(wr + c0 + 4);
        acc = mfma16(pack8(xa, xb), pack8(wa, wb), acc);
    }
    int col = n0 + lr;
    float bo = qkv_b[col];
    int part = col >> 8, o = col & 255;
#pragma unroll
    for (int r = 0; r < 4; ++r) {
        int m = m0 + lg * 4 + r;
        float v = acc[r] + bo;
        if (part == 0) {
            qb[(size_t)m * DD + o] = v * QSCALE;
        } else if (part == 1) {
            kbbf[(size_t)m * DD + o] = (__bf16)v;
        } else {
            int b = (m >= NN) ? 1 : 0;
            int n = m - b * NN;
            vT[(size_t)b * DD * NN + (size_t)o * NN + n] = (__bf16)v;
        }
    }
}

// ---------------- Kernel 2a: scores + e, gi-PAIR per block (r14 proven) ----------------
// grid = 768 (384 pairs x 2 j-halves), 256 thr.
__global__ __launch_bounds__(256, 4) void k2a_kernel(
    const float* __restrict__ rb_b1, const __bf16* __restrict__ w2neg,
    const float* __restrict__ rb_b2,
    const float* __restrict__ qb, const __bf16* __restrict__ kbbf,
    const __bf16* __restrict__ Arb,
    __bf16* __restrict__ eG, float* __restrict__ Zpart)
{
    __shared__ __align__(16) __bf16 qsbf[2][DD];
    __shared__ __align__(16) float Apr[2][DD];
    __shared__ __align__(16) __bf16 w2bf[HH * W2_ST];
    __shared__ float redsm[4][2][HH];

    int tid = threadIdx.x;
    int bid = blockIdx.x;
    int gp = bid >> 1, half = bid & 1;
    int gi0 = gp * 2;
    int b = (gp >= 192) ? 1 : 0;

    qsbf[0][tid] = (__bf16)qb[(size_t)gi0 * DD + tid];
    qsbf[1][tid] = (__bf16)qb[(size_t)(gi0 + 1) * DD + tid];
    float b1l = rb_b1[tid] * LOG2E;
    Apr[0][tid] = (float)Arb[(size_t)gi0 * DD + tid] + b1l;
    Apr[1][tid] = (float)Arb[(size_t)(gi0 + 1) * DD + tid] + b1l;
    {
        int idx = tid * 8;
        *(bf16x8*)&w2bf[(idx >> 8) * W2_ST + (idx & 255)] =
            *(const bf16x8*)(w2neg + idx);
    }
    __syncthreads();

    int l = tid & 63, wv = tid >> 6;
    int lr = l & 15, lg = l >> 4;
    float rb2l = rb_b2[lr & 7] * LOG2E;

    int jb0 = half * 192 + wv * 16;
    int jb1 = jb0 + 64, jb2 = jb0 + 128;
    const __bf16* arbB = Arb + (size_t)b * NN * DD;
    const __bf16* kbB  = kbbf + (size_t)b * NN * DD;
    const __bf16* ar0 = arbB + (size_t)(jb0 + lr) * DD;
    const __bf16* ar1 = arbB + (size_t)(jb1 + lr) * DD;
    const __bf16* ar2 = arbB + (size_t)(jb2 + lr) * DD;
    const __bf16* kr0 = kbB  + (size_t)(jb0 + lr) * DD;
    const __bf16* kr1 = kbB  + (size_t)(jb1 + lr) * DD;
    const __bf16* kr2 = kbB  + (size_t)(jb2 + lr) * DD;
    const __bf16* wfp = &w2bf[(lr & 7) * W2_ST];

    bf16x8 qf0_reg = *(const bf16x8*)&qsbf[0][(lr & 7) * 32 + lg * 8];
    bf16x8 qf1_reg = *(const bf16x8*)&qsbf[1][(lr & 7) * 32 + lg * 8];
    bf16x8 zero8;
#pragma unroll
    for (int e = 0; e < 8; ++e) zero8[e] = (__bf16)0.f;

    f32x4 zzz = {0.f, 0.f, 0.f, 0.f};
    f32x4 a00 = zzz, a01 = zzz, a02 = zzz;   // gi0
    f32x4 a10 = zzz, a11 = zzz, a12 = zzz;   // gi1
#pragma unroll
    for (int ks = 0; ks < 8; ++ks) {
        int c0 = ks * 32 + lg * 8;
        bf16x8 v0 = *(const bf16x8*)(ar0 + c0);
        bf16x8 v1 = *(const bf16x8*)(ar1 + c0);
        bf16x8 v2 = *(const bf16x8*)(ar2 + c0);
        bf16x8 k0 = *(const bf16x8*)(kr0 + c0);
        bf16x8 k1 = *(const bf16x8*)(kr1 + c0);
        bf16x8 k2 = *(const bf16x8*)(kr2 + c0);
        bf16x8 wf = *(const bf16x8*)(wfp + c0);
        float4 p00 = *(const float4*)&Apr[0][c0];
        float4 p01 = *(const float4*)&Apr[0][c0 + 4];
        float4 p10 = *(const float4*)&Apr[1][c0];
        float4 p11 = *(const float4*)&Apr[1][c0 + 4];
        bf16x8 q0 = (lr == ks) ? qf0_reg : zero8;
        bf16x8 q1 = (lr == ks) ? qf1_reg : zero8;
        a00 = mfma16(hid8(v0, p00, p01), wf, a00);
        a10 = mfma16(hid8(v0, p10, p11), wf, a10);
        a01 = mfma16(hid8(v1, p00, p01), wf, a01);
        a11 = mfma16(hid8(v1, p10, p11), wf, a11);
        a02 = mfma16(hid8(v2, p00, p01), wf, a02);
        a12 = mfma16(hid8(v2, p10, p11), wf, a12);
        a00 = mfma16(k0, q0, a00);
        a10 = mfma16(k0, q1, a10);
        a01 = mfma16(k1, q0, a01);
        a11 = mfma16(k1, q1, a11);
        a02 = mfma16(k2, q0, a02);
        a12 = mfma16(k2, q1, a12);
    }

    float z0 = 0.f, z1 = 0.f;
#define FINTILE(ACC, GI, JB, ZACC) { \
        float e0 = __builtin_amdgcn_exp2f(ACC[0] + rb2l); \
        float e1 = __builtin_amdgcn_exp2f(ACC[1] + rb2l); \
        float e2 = __builtin_amdgcn_exp2f(ACC[2] + rb2l); \
        float e3 = __builtin_amdgcn_exp2f(ACC[3] + rb2l); \
        if (lr < 8) { \
            bf16x4 ev; \
            ev[0] = (__bf16)e0; ev[1] = (__bf16)e1; \
            ev[2] = (__bf16)e2; ev[3] = (__bf16)e3; \
            *(bf16x4*)&eG[((size_t)(GI) * HH + lr) * NN + (JB) + lg * 4] = ev; \
        } \
        float zs = e0 + e1 + e2 + e3; \
        zs += __shfl_xor(zs, 16); \
        zs += __shfl_xor(zs, 32); \
        ZACC += zs; }
    FINTILE(a00, gi0,     jb0, z0)
    FINTILE(a01, gi0,     jb1, z0)
    FINTILE(a02, gi0,     jb2, z0)
    FINTILE(a10, gi0 + 1, jb0, z1)
    FINTILE(a11, gi0 + 1, jb1, z1)
    FINTILE(a12, gi0 + 1, jb2, z1)
#undef FINTILE
    if (lg == 0 && lr < 8) {
        redsm[wv][0][lr] = z0;
        redsm[wv][1][lr] = z1;
    }
    __syncthreads();
    if (tid < 16) {
        int g = tid >> 3, h = tid & 7;
        Zpart[((size_t)(gi0 + g) * 2 + half) * 8 + h] =
            redsm[0][g][h] + redsm[1][g][h] + redsm[2][g][h] + redsm[3][g][h];
    }
}

// ---------------- Kernel 2b: T/base, gi-QUAD x c-QUARTER ----------------
// grid = 768 (192 quads x 4 c-quarters), 256 thr, 12 K-iters (full j).
// Per iter: 2 global gathers (av, tv shared by 4 queries) + 2 LDS ef reads.
__global__ __launch_bounds__(256, 4) void k2b_kernel(
    const float* __restrict__ rv_b1, const float* __restrict__ rv_w2,
    const __bf16* __restrict__ vT, const __bf16* __restrict__ ArvT,
    const __bf16* __restrict__ Arv, const __bf16* __restrict__ eG,
    float* __restrict__ rcpart, float* __restrict__ basef)
{
    __shared__ __align__(16) __bf16 els[32 * EB_ST];    // 25 KB: 32 e-rows (4 queries x 8 heads)
    __shared__ __align__(16) __bf16 Tb[4][HH * TB_ST];  // 4.3 KB
    __shared__ float aps[4][64];

    int tid = threadIdx.x;
    int bid = blockIdx.x;
    int gq = bid >> 2, cq = bid & 3;
    int gi0 = gq * 4;
    int b = (gq >= 96) ? 1 : 0;

    // stage 32 e-rows, coalesced (48 chunks of 16B per row)
    {
        const __bf16* src = eG + (size_t)(gi0 * 8) * NN;
#pragma unroll
        for (int s = 0; s < 6; ++s) {
            int idx = tid + s * 256;
            int r = idx / 48, cc = idx - r * 48;
            *(bf16x8*)&els[r * EB_ST + cc * 8] =
                *(const bf16x8*)(src + (size_t)r * NN + cc * 8);
        }
    }
    {
        int g = tid >> 6, cl0 = tid & 63;
        aps[g][cl0] = (float)Arv[(size_t)(gi0 + g) * DD + cq * 64 + cl0]
                    + rv_b1[cq * 64 + cl0] * LOG2E;
    }
    __syncthreads();

    int l = tid & 63, wv = tid >> 6;
    int lr = l & 15, lg = l >> 4;
    int cl = wv * 16 + lr;            // 0..63
    int cglob = cq * 64 + cl;

    float ap0 = aps[0][cl], ap1 = aps[1][cl], ap2 = aps[2][cl], ap3 = aps[3][cl];
    const __bf16* vr = ArvT + (size_t)cglob * RN + b * NN;
    const __bf16* tv = vT + (size_t)b * DD * NN + (size_t)cglob * NN;
    const __bf16* e0p = &els[lr * EB_ST];
    const __bf16* e1p = &els[(16 + lr) * EB_ST];

    f32x4 zz = {0.f, 0.f, 0.f, 0.f};
    f32x4 T0 = zz, T1 = zz, T2 = zz, T3 = zz, Bk0 = zz, Bk1 = zz;
#pragma unroll
    for (int ks = 0; ks < 12; ++ks) {
        int j0 = ks * 32 + lg * 8;
        bf16x8 ef0 = *(const bf16x8*)(e0p + j0);   // rows 0-15: gi0,gi1
        bf16x8 ef1 = *(const bf16x8*)(e1p + j0);   // rows 16-31: gi2,gi3
        bf16x8 av  = *(const bf16x8*)(vr + j0);
        bf16x8 w   = *(const bf16x8*)(tv + j0);
        T0 = mfma16(ef0, hid8s(av, ap0), T0);      // valid D rows 0-7  (gi0)
        T1 = mfma16(ef0, hid8s(av, ap1), T1);      // valid D rows 8-15 (gi1)
        T2 = mfma16(ef1, hid8s(av, ap2), T2);      // valid D rows 0-7  (gi2)
        T3 = mfma16(ef1, hid8s(av, ap3), T3);      // valid D rows 8-15 (gi3)
        Bk0 = mfma16(ef0, w, Bk0);                 // packed base gi0/gi1
        Bk1 = mfma16(ef1, w, Bk1);                 // packed base gi2/gi3
    }

    // T extraction -> Tb (bf16, * -ln2). Even g: rows 0-7 (lg<2); odd g: rows 8-15.
    if (lg < 2) {
#pragma unroll
        for (int r = 0; r < 4; ++r) {
            int h = lg * 4 + r;
            Tb[0][h * TB_ST + cl] = (__bf16)(T0[r] * NLN2);
            Tb[2][h * TB_ST + cl] = (__bf16)(T2[r] * NLN2);
        }
    } else {
#pragma unroll
        for (int r = 0; r < 4; ++r) {
            int h = (lg - 2) * 4 + r;
            Tb[1][h * TB_ST + cl] = (__bf16)(T1[r] * NLN2);
            Tb[3][h * TB_ST + cl] = (__bf16)(T3[r] * NLN2);
        }
    }
    // base: col cglob needs D row h0 (even g) / 8+h0 (odd g), h0 = cglob>>5 (wave-uniform)
    {
        int h0 = cglob >> 5;
        int rr = h0 & 3;
        if (lg == (h0 >> 2)) {
            basef[(size_t)(gi0 + 0) * DD + cglob] = selv(Bk0, rr);
            basef[(size_t)(gi0 + 2) * DD + cglob] = selv(Bk1, rr);
        }
        if (lg == 2 + (h0 >> 2)) {
            basef[(size_t)(gi0 + 1) * DD + cglob] = selv(Bk0, rr);
            basef[(size_t)(gi0 + 3) * DD + cglob] = selv(Bk1, rr);
        }
    }
    __syncthreads();

    // rc partials over this c-quarter for 4 queries: o = tid
    {
        int o = tid, h = o >> 5;
        const float4* w2p = (const float4*)(rv_w2 + (size_t)o * DD);
#pragma unroll
        for (int g = 0; g < 4; ++g) {
            const __bf16* trow = &Tb[g][h * TB_ST];
            float a = 0.f;
#pragma unroll 4
            for (int cc2 = 0; cc2 < 16; ++cc2) {
                float4 w4 = w2p[cq * 16 + cc2];
                bf16x4 u = *(const bf16x4*)&trow[cc2 * 4];
                a += w4.x * (float)u[0] + w4.y * (float)u[1]
                   + w4.z * (float)u[2] + w4.w * (float)u[3];
            }
            rcpart[((size_t)cq * RN + gi0 + g) * DD + o] = a;
        }
    }
}

// ---------------- Kernel 2c: combine. grid = 768, 256 thr ----------------
__global__ __launch_bounds__(256) void k2c_kernel(
    const float* __restrict__ rcpart, const float* __restrict__ basef,
    const float* __restrict__ Zpart, const float* __restrict__ rv_b2,
    float* __restrict__ out)
{
    int gi = blockIdx.x, o = threadIdx.x, h = o >> 5;
    float z = Zpart[(size_t)gi * 16 + h] + Zpart[(size_t)gi * 16 + 8 + h];
    size_t io = (size_t)gi * DD + o;
    const size_t SL = (size_t)RN * DD;
    float rc = rcpart[io] + rcpart[SL + io] + rcpart[2 * SL + io] + rcpart[3 * SL + io];
    out[io] = (rc + basef[io]) * __builtin_amdgcn_rcpf(z) + rv_b2[o];
}

extern "C" void kernel_launch(void* const* d_in, const int* in_sizes, int n_in,
                              void* d_out, int out_size, void* d_ws, size_t ws_size,
                              hipStream_t stream) {
    const float* x      = (const float*)d_in[0];
    const float* coords = (const float*)d_in[1];
    const float* qkv_w  = (const float*)d_in[2];
    const float* qkv_b  = (const float*)d_in[3];
    const float* rb_w1  = (const float*)d_in[4];
    const float* rb_b1  = (const float*)d_in[5];
    const float* rb_w2  = (const float*)d_in[6];
    const float* rb_b2  = (const float*)d_in[7];
    const float* rv_w1  = (const float*)d_in[8];
    const float* rv_b1  = (const float*)d_in[9];
    const float* rv_w2  = (const float*)d_in[10];
    const float* rv_b2  = (const float*)d_in[11];
    float* out = (float*)d_out;

    float* ws = (float*)d_ws;
    const int PER = RN * DD;               // 196608
    float* qb = ws;                        // PER f32
    __bf16* bfb  = (__bf16*)(ws + PER);
    __bf16* kbbf = bfb;                    // PER bf16
    __bf16* vTb  = bfb + PER;              // PER bf16
    __bf16* Arb  = bfb + 2 * PER;          // PER bf16
    __bf16* ArvT = bfb + 3 * PER;          // PER bf16
    __bf16* Arv  = bfb + 4 * PER;          // PER bf16 (row-major copy)
    __bf16* eG   = bfb + 5 * (size_t)PER;  // RN*HH*NN bf16
    float* Zpart = (float*)(eG + (size_t)RN * HH * NN);   // RN*2*HH f32
    float* basef = Zpart + (size_t)RN * 2 * HH;           // PER f32
    float* rcpart = basef + PER;                          // 4*PER f32
    __bf16* w2neg = (__bf16*)(rcpart + 4 * (size_t)PER);  // 2048 bf16

    prep_kernel<<<1345, 256, 0, stream>>>(x, coords, qkv_w, qkv_b,
                                          rb_w1, rv_w1, rb_w2,
                                          qb, kbbf, vTb, Arb, ArvT, Arv, w2neg);
    k2a_kernel<<<RN, 256, 0, stream>>>(rb_b1, w2neg, rb_b2,
                                       qb, kbbf, Arb, eG, Zpart);
    k2b_kernel<<<RN, 256, 0, stream>>>(rv_b1, rv_w2,
                                       vTb, ArvT, Arv, eG, rcpart, basef);
    k2c_kernel<<<RN, 256, 0, stream>>>(rcpart, basef, Zpart, rv_b2, out);
}

// Round 17
// 71.602 us; speedup vs baseline: 1.5166x; 1.1556x over previous
//
#include <hip/hip_runtime.h>
#include <math.h>

#define BB 2
#define NN 384
#define DD 256
#define HH 8
#define RN (BB * NN)   // 768
#define INV_SQRT_HD 0.17677669529663687f   // 1/sqrt(32)
#define LOG2E 1.4426950408889634f
#define NLN2 -0.6931471805599453f
#define QSCALE (INV_SQRT_HD * LOG2E)

#define W2_ST 264   // bf16 stride, rb_w2 rows in LDS
#define T_ST  264   // f32 stride, T rows
#define EB_ST 392   // bf16 stride, staged e rows

typedef float f32x4 __attribute__((ext_vector_type(4)));
typedef __bf16 bf16x8 __attribute__((ext_vector_type(8)));
typedef __bf16 bf16x4 __attribute__((ext_vector_type(4)));

__device__ __forceinline__ f32x4 mfma16(bf16x8 a, bf16x8 b, f32x4 c) {
    return __builtin_amdgcn_mfma_f32_16x16x32_bf16(a, b, c, 0, 0, 0);
}

// fragment-major index maps (one wave load = 64 lanes x 16B contiguous)
// A-operand tiles (16 j-rows x 32 c): lane = ((c%32)/8)*16 + j%16, elem = c%8
__device__ __forceinline__ size_t fA(int b, int j, int c) {
    return ((((size_t)b * 24 + (j >> 4)) * 8 + (c >> 5)) * 64
            + (((c & 31) >> 3) << 4) + (j & 15)) * 8 + (c & 7);
}
// B-operand tiles (16 c-cols x 32 j): lane = ((j%32)/8)*16 + c%16, elem = j%8
__device__ __forceinline__ size_t fB(int b, int c, int j) {
    return ((((size_t)b * 16 + (c >> 4)) * 12 + (j >> 5)) * 64
            + (((j & 31) >> 3) << 4) + (c & 15)) * 8 + (j & 7);
}

// d = av' - ap' (primes pre-scaled by log2e) = -x*log2e.
// returns -log2e*silu(x); folds: k2a w2bf=-rb_w2; k2b Tl *= -ln2.
__device__ __forceinline__ float hidp(float d) {
    float e = __builtin_amdgcn_exp2f(d);
    return d * __builtin_amdgcn_rcpf(1.0f + e);
}
__device__ __forceinline__ bf16x8 hid8(bf16x8 av, float4 a0, float4 a1) {
    bf16x8 r;
    r[0] = (__bf16)hidp((float)av[0] - a0.x);
    r[1] = (__bf16)hidp((float)av[1] - a0.y);
    r[2] = (__bf16)hidp((float)av[2] - a0.z);
    r[3] = (__bf16)hidp((float)av[3] - a0.w);
    r[4] = (__bf16)hidp((float)av[4] - a1.x);
    r[5] = (__bf16)hidp((float)av[5] - a1.y);
    r[6] = (__bf16)hidp((float)av[6] - a1.z);
    r[7] = (__bf16)hidp((float)av[7] - a1.w);
    return r;
}
__device__ __forceinline__ bf16x8 hid8s(bf16x8 av, float a) {
    bf16x8 r;
#pragma unroll
    for (int q = 0; q < 8; ++q) r[q] = (__bf16)hidp((float)av[q] - a);
    return r;
}
__device__ __forceinline__ bf16x8 pack8(float4 a, float4 b) {
    bf16x8 r;
    r[0] = (__bf16)a.x; r[1] = (__bf16)a.y; r[2] = (__bf16)a.z; r[3] = (__bf16)a.w;
    r[4] = (__bf16)b.x; r[5] = (__bf16)b.y; r[6] = (__bf16)b.z; r[7] = (__bf16)b.w;
    return r;
}
__device__ __forceinline__ float selv(f32x4 v, int r) {
    return (r == 0) ? v[0] : (r == 1) ? v[1] : (r == 2) ? v[2] : v[3];
}

// ---------------- Kernel 1: fused prep ----------------
// [0,576): qkv MFMA -> qb / Kbf(frag) / Vf(frag).
// [576,1344): A-arrays -> Arb,Arv (row) + Abf,Avf (frag).  [1344]: w2neg.
__global__ __launch_bounds__(256) void prep_kernel(
    const float* __restrict__ x, const float* __restrict__ coords,
    const float* __restrict__ qkv_w, const float* __restrict__ qkv_b,
    const float* __restrict__ rb_w1, const float* __restrict__ rv_w1,
    const float* __restrict__ rb_w2,
    float* __restrict__ qb,
    __bf16* __restrict__ Arb, __bf16* __restrict__ Arv,
    __bf16* __restrict__ Abf, __bf16* __restrict__ Kbf,
    __bf16* __restrict__ Avf, __bf16* __restrict__ Vf,
    __bf16* __restrict__ w2neg)
{
    int bid = blockIdx.x, tid = threadIdx.x;
    if (bid >= 1344) {
        int idx = tid * 8;
        float4 wa = *(const float4*)(rb_w2 + idx);
        float4 wb = *(const float4*)(rb_w2 + idx + 4);
        float4 na = make_float4(-wa.x, -wa.y, -wa.z, -wa.w);
        float4 nb = make_float4(-wb.x, -wb.y, -wb.z, -wb.w);
        *(bf16x8*)(w2neg + idx) = pack8(na, nb);
        return;
    }
    if (bid >= 576) {
        int r = bid - 576, c = tid;
        int bb = r / NN, jl = r - bb * NN;
        float cx = coords[r * 3 + 0], cy = coords[r * 3 + 1], cz = coords[r * 3 + 2];
        float ab = (cx * rb_w1[c * 3] + cy * rb_w1[c * 3 + 1] + cz * rb_w1[c * 3 + 2]) * LOG2E;
        float av = (cx * rv_w1[c * 3] + cy * rv_w1[c * 3 + 1] + cz * rv_w1[c * 3 + 2]) * LOG2E;
        Arb[r * DD + c] = (__bf16)ab;
        Arv[r * DD + c] = (__bf16)av;
        Abf[fA(bb, jl, c)] = (__bf16)ab;
        Avf[fB(bb, c, jl)] = (__bf16)av;
        return;
    }
    int mt = bid % 48, nb = bid / 48;
    int w = tid >> 6, l = tid & 63, lr = l & 15, lg = l >> 4;
    int m0 = mt * 16, n0 = nb * 64 + w * 16;
    const float* xr = x + (size_t)(m0 + lr) * DD;
    const float* wr = qkv_w + (size_t)(n0 + lr) * DD;
    f32x4 acc = {0.f, 0.f, 0.f, 0.f};
#pragma unroll
    for (int ks = 0; ks < 8; ++ks) {
        int c0 = ks * 32 + lg * 8;
        float4 xa = *(const float4*)(xr + c0);
        float4 xb = *(const float4*)(xr + c0 + 4);
        float4 wa = *(const float4*)(wr + c0);
        float4 wb = *(const float4*)(wr + c0 + 4);
        acc = mfma16(pack8(xa, xb), pack8(wa, wb), acc);
    }
    int col = n0 + lr;
    float bo = qkv_b[col];
    int part = col >> 8, o = col & 255;
#pragma unroll
    for (int r = 0; r < 4; ++r) {
        int m = m0 + lg * 4 + r;
        float v = acc[r] + bo;
        int bb = (m >= NN) ? 1 : 0;
        int n = m - bb * NN;
        if (part == 0) {
            qb[(size_t)m * DD + o] = v * QSCALE;
        } else if (part == 1) {
            Kbf[fA(bb, n, o)] = (__bf16)v;
        } else {
            Vf[fB(bb, o, n)] = (__bf16)v;
        }
    }
}

// ---------------- Kernel 2a: scores + e, gi-PAIR per block ----------------
// grid = 768 (384 pairs x 2 j-halves), 256 thr. Fragment-major coalesced streams.
__global__ __launch_bounds__(256, 4) void k2a_kernel(
    const float* __restrict__ rb_b1, const __bf16* __restrict__ w2neg,
    const float* __restrict__ rb_b2,
    const float* __restrict__ qb, const __bf16* __restrict__ Kbf,
    const __bf16* __restrict__ Abf, const __bf16* __restrict__ Arb,
    __bf16* __restrict__ eG, float* __restrict__ Zpart)
{
    __shared__ __align__(16) __bf16 qsbf[2][DD];
    __shared__ __align__(16) float Apr[2][DD];
    __shared__ __align__(16) __bf16 w2bf[HH * W2_ST];
    __shared__ float redsm[4][2][HH];

    int tid = threadIdx.x;
    int bid = blockIdx.x;
    int gp = bid >> 1, half = bid & 1;
    int gi0 = gp * 2;
    int b = (gp >= 192) ? 1 : 0;

    qsbf[0][tid] = (__bf16)qb[(size_t)gi0 * DD + tid];
    qsbf[1][tid] = (__bf16)qb[(size_t)(gi0 + 1) * DD + tid];
    float b1l = rb_b1[tid] * LOG2E;
    Apr[0][tid] = (float)Arb[(size_t)gi0 * DD + tid] + b1l;
    Apr[1][tid] = (float)Arb[(size_t)(gi0 + 1) * DD + tid] + b1l;
    {
        int idx = tid * 8;
        *(bf16x8*)&w2bf[(idx >> 8) * W2_ST + (idx & 255)] =
            *(const bf16x8*)(w2neg + idx);
    }
    __syncthreads();

    int l = tid & 63, wv = tid >> 6;
    int lr = l & 15, lg = l >> 4;
    float rb2l = rb_b2[lr & 7] * LOG2E;

    int jb0 = half * 192 + wv * 16;
    int jb1 = jb0 + 64, jb2 = jb0 + 128;
    int jt0 = half * 12 + wv;   // j-tile indices jt0, jt0+4, jt0+8
    const __bf16* pA0 = Abf + ((size_t)(b * 24 + jt0) * 8) * 512 + (size_t)l * 8;
    const __bf16* pA1 = pA0 + (size_t)4 * 4096;
    const __bf16* pA2 = pA0 + (size_t)8 * 4096;
    const __bf16* pK0 = Kbf + ((size_t)(b * 24 + jt0) * 8) * 512 + (size_t)l * 8;
    const __bf16* pK1 = pK0 + (size_t)4 * 4096;
    const __bf16* pK2 = pK0 + (size_t)8 * 4096;
    const __bf16* wfp = &w2bf[(lr & 7) * W2_ST];

    bf16x8 qf0_reg = *(const bf16x8*)&qsbf[0][(lr & 7) * 32 + lg * 8];
    bf16x8 qf1_reg = *(const bf16x8*)&qsbf[1][(lr & 7) * 32 + lg * 8];
    bf16x8 zero8;
#pragma unroll
    for (int e = 0; e < 8; ++e) zero8[e] = (__bf16)0.f;

    f32x4 zzz = {0.f, 0.f, 0.f, 0.f};
    f32x4 a00 = zzz, a01 = zzz, a02 = zzz;   // gi0
    f32x4 a10 = zzz, a11 = zzz, a12 = zzz;   // gi1
#pragma unroll
    for (int ks = 0; ks < 8; ++ks) {
        int c0 = ks * 32 + lg * 8;
        size_t fo = (size_t)ks * 512;
        bf16x8 v0 = *(const bf16x8*)(pA0 + fo);
        bf16x8 v1 = *(const bf16x8*)(pA1 + fo);
        bf16x8 v2 = *(const bf16x8*)(pA2 + fo);
        bf16x8 k0 = *(const bf16x8*)(pK0 + fo);
        bf16x8 k1 = *(const bf16x8*)(pK1 + fo);
        bf16x8 k2 = *(const bf16x8*)(pK2 + fo);
        bf16x8 wf = *(const bf16x8*)(wfp + c0);
        float4 p00 = *(const float4*)&Apr[0][c0];
        float4 p01 = *(const float4*)&Apr[0][c0 + 4];
        float4 p10 = *(const float4*)&Apr[1][c0];
        float4 p11 = *(const float4*)&Apr[1][c0 + 4];
        bf16x8 q0 = (lr == ks) ? qf0_reg : zero8;
        bf16x8 q1 = (lr == ks) ? qf1_reg : zero8;
        a00 = mfma16(hid8(v0, p00, p01), wf, a00);
        a10 = mfma16(hid8(v0, p10, p11), wf, a10);
        a01 = mfma16(hid8(v1, p00, p01), wf, a01);
        a11 = mfma16(hid8(v1, p10, p11), wf, a11);
        a02 = mfma16(hid8(v2, p00, p01), wf, a02);
        a12 = mfma16(hid8(v2, p10, p11), wf, a12);
        a00 = mfma16(k0, q0, a00);
        a10 = mfma16(k0, q1, a10);
        a01 = mfma16(k1, q0, a01);
        a11 = mfma16(k1, q1, a11);
        a02 = mfma16(k2, q0, a02);
        a12 = mfma16(k2, q1, a12);
    }

    float z0 = 0.f, z1 = 0.f;
#define FINTILE(ACC, GI, JB, ZACC) { \
        float e0 = __builtin_amdgcn_exp2f(ACC[0] + rb2l); \
        float e1 = __builtin_amdgcn_exp2f(ACC[1] + rb2l); \
        float e2 = __builtin_amdgcn_exp2f(ACC[2] + rb2l); \
        float e3 = __builtin_amdgcn_exp2f(ACC[3] + rb2l); \
        if (lr < 8) { \
            bf16x4 ev; \
            ev[0] = (__bf16)e0; ev[1] = (__bf16)e1; \
            ev[2] = (__bf16)e2; ev[3] = (__bf16)e3; \
            *(bf16x4*)&eG[((size_t)(GI) * HH + lr) * NN + (JB) + lg * 4] = ev; \
        } \
        float zs = e0 + e1 + e2 + e3; \
        zs += __shfl_xor(zs, 16); \
        zs += __shfl_xor(zs, 32); \
        ZACC += zs; }
    FINTILE(a00, gi0,     jb0, z0)
    FINTILE(a01, gi0,     jb1, z0)
    FINTILE(a02, gi0,     jb2, z0)
    FINTILE(a10, gi0 + 1, jb0, z1)
    FINTILE(a11, gi0 + 1, jb1, z1)
    FINTILE(a12, gi0 + 1, jb2, z1)
#undef FINTILE
    if (lg == 0 && lr < 8) {
        redsm[wv][0][lr] = z0;
        redsm[wv][1][lr] = z1;
    }
    __syncthreads();
    if (tid < 16) {
        int g = tid >> 3, h = tid & 7;
        Zpart[((size_t)(gi0 + g) * 2 + half) * 8 + h] =
            redsm[0][g][h] + redsm[1][g][h] + redsm[2][g][h] + redsm[3][g][h];
    }
}

// ---------------- Kernel 2b: T/base, gi-PAIR packed, frag-major streams ----------------
// grid = 768 (384 pairs x 2 c-halves), 256 thr, 12 K-iters.
__global__ __launch_bounds__(256, 4) void k2b_kernel(
    const float* __restrict__ rv_b1, const float* __restrict__ rv_w2,
    const __bf16* __restrict__ Avf, const __bf16* __restrict__ Vf,
    const __bf16* __restrict__ Arv, const __bf16* __restrict__ eG,
    float* __restrict__ rcpart, float* __restrict__ basef)
{
    __shared__ __align__(16) float Apv[2][DD];
    __shared__ __align__(16) float Tl[2][HH * T_ST];
    __shared__ __align__(16) __bf16 els[16 * EB_ST];

    int tid = threadIdx.x;
    int bid = blockIdx.x;
    int gp = bid >> 1, ch = bid & 1;
    int gi0 = gp * 2;
    int b = (gp >= 192) ? 1 : 0;

    float b1l = rv_b1[tid] * LOG2E;
    Apv[0][tid] = (float)Arv[(size_t)gi0 * DD + tid] + b1l;
    Apv[1][tid] = (float)Arv[(size_t)(gi0 + 1) * DD + tid] + b1l;
    // stage the 16 shared e-rows (rows 0-7: gi0, 8-15: gi1)
    {
        int r = tid >> 4, cg = tid & 15;
        const __bf16* src = eG + (size_t)(gi0 * 8 + r) * NN;
#pragma unroll
        for (int s = 0; s < 3; ++s) {
            int col = s * 128 + cg * 8;
            *(bf16x8*)&els[r * EB_ST + col] = *(const bf16x8*)(src + col);
        }
    }
    __syncthreads();

    int l = tid & 63, wv = tid >> 6;
    int lr = l & 15, lg = l >> 4;

    int c0 = ch * 128 + wv * 16 + lr;
    int c1 = c0 + 64;
    float ap00 = Apv[0][c0], ap01 = Apv[0][c1];
    float ap10 = Apv[1][c0], ap11 = Apv[1][c1];
    int t0 = ch * 8 + wv;   // c-tile indices t0, t0+4
    const __bf16* pAv0 = Avf + ((size_t)(b * 16 + t0) * 12) * 512 + (size_t)l * 8;
    const __bf16* pAv1 = pAv0 + (size_t)4 * 6144;
    const __bf16* pV0  = Vf + ((size_t)(b * 16 + t0) * 12) * 512 + (size_t)l * 8;
    const __bf16* pV1  = pV0 + (size_t)4 * 6144;

    f32x4 zzz = {0.f, 0.f, 0.f, 0.f};
    f32x4 T00 = zzz, T01 = zzz, T10 = zzz, T11 = zzz;
    f32x4 B0 = zzz, B1 = zzz;
#pragma unroll
    for (int ks = 0; ks < 12; ++ks) {
        int j0 = ks * 32 + lg * 8;
        size_t fo = (size_t)ks * 512;
        bf16x8 ef  = *(const bf16x8*)&els[lr * EB_ST + j0];
        bf16x8 av0 = *(const bf16x8*)(pAv0 + fo);
        bf16x8 av1 = *(const bf16x8*)(pAv1 + fo);
        bf16x8 w0  = *(const bf16x8*)(pV0 + fo);
        bf16x8 w1  = *(const bf16x8*)(pV1 + fo);
        T00 = mfma16(ef, hid8s(av0, ap00), T00);   // valid rows 0-7  (gi0)
        T01 = mfma16(ef, hid8s(av1, ap01), T01);
        T10 = mfma16(ef, hid8s(av0, ap10), T10);   // valid rows 8-15 (gi1)
        T11 = mfma16(ef, hid8s(av1, ap11), T11);
        B0  = mfma16(ef, w0, B0);                  // packed: rows 0-7 gi0, 8-15 gi1
        B1  = mfma16(ef, w1, B1);
    }

    if (lg < 2) {
#pragma unroll
        for (int r = 0; r < 4; ++r) {
            int h = lg * 4 + r;
            Tl[0][h * T_ST + c0] = T00[r] * NLN2;
            Tl[0][h * T_ST + c1] = T01[r] * NLN2;
        }
    } else {
#pragma unroll
        for (int r = 0; r < 4; ++r) {
            int h = (lg - 2) * 4 + r;
            Tl[1][h * T_ST + c0] = T10[r] * NLN2;
            Tl[1][h * T_ST + c1] = T11[r] * NLN2;
        }
    }
    // base: D col c needs row h=c>>5 (gi0) and 8+h (gi1)
    {
        int h0 = c0 >> 5;
        if (lg == (h0 >> 2))     basef[(size_t)gi0 * DD + c0]       = selv(B0, h0 & 3);
        if (lg == 2 + (h0 >> 2)) basef[(size_t)(gi0 + 1) * DD + c0] = selv(B0, h0 & 3);
        int h1 = c1 >> 5;
        if (lg == (h1 >> 2))     basef[(size_t)gi0 * DD + c1]       = selv(B1, h1 & 3);
        if (lg == 2 + (h1 >> 2)) basef[(size_t)(gi0 + 1) * DD + c1] = selv(B1, h1 & 3);
    }
    __syncthreads();

    // rc partial over this c-half: o = tid
    {
        int o = tid, h = o >> 5;
        const float4* w2p = (const float4*)(rv_w2 + (size_t)o * DD);
        const float* t0p = &Tl[0][h * T_ST];
        const float* t1p = &Tl[1][h * T_ST];
        float a0 = 0.f, a1 = 0.f;
#pragma unroll 4
        for (int cc = 0; cc < 32; ++cc) {
            int cidx = ch * 32 + cc;
            float4 wv4 = w2p[cidx];
            float4 u0 = *(const float4*)&t0p[cidx * 4];
            float4 u1 = *(const float4*)&t1p[cidx * 4];
            a0 += wv4.x * u0.x + wv4.y * u0.y + wv4.z * u0.z + wv4.w * u0.w;
            a1 += wv4.x * u1.x + wv4.y * u1.y + wv4.z * u1.z + wv4.w * u1.w;
        }
        rcpart[((size_t)ch * RN + gi0) * DD + o] = a0;
        rcpart[((size_t)ch * RN + gi0 + 1) * DD + o] = a1;
    }
}

// ---------------- Kernel 2c: combine. grid = 768, 256 thr ----------------
__global__ __launch_bounds__(256) void k2c_kernel(
    const float* __restrict__ rcpart, const float* __restrict__ basef,
    const float* __restrict__ Zpart, const float* __restrict__ rv_b2,
    float* __restrict__ out)
{
    int gi = blockIdx.x, o = threadIdx.x, h = o >> 5;
    float z = Zpart[(size_t)gi * 16 + h] + Zpart[(size_t)gi * 16 + 8 + h];
    float rc = rcpart[(size_t)gi * DD + o] + rcpart[((size_t)RN + gi) * DD + o];
    out[(size_t)gi * DD + o] =
        (rc + basef[(size_t)gi * DD + o]) * __builtin_amdgcn_rcpf(z) + rv_b2[o];
}

extern "C" void kernel_launch(void* const* d_in, const int* in_sizes, int n_in,
                              void* d_out, int out_size, void* d_ws, size_t ws_size,
                              hipStream_t stream) {
    const float* x      = (const float*)d_in[0];
    const float* coords = (const float*)d_in[1];
    const float* qkv_w  = (const float*)d_in[2];
    const float* qkv_b  = (const float*)d_in[3];
    const float* rb_w1  = (const float*)d_in[4];
    const float* rb_b1  = (const float*)d_in[5];
    const float* rb_w2  = (const float*)d_in[6];
    const float* rb_b2  = (const float*)d_in[7];
    const float* rv_w1  = (const float*)d_in[8];
    const float* rv_b1  = (const float*)d_in[9];
    const float* rv_w2  = (const float*)d_in[10];
    const float* rv_b2  = (const float*)d_in[11];
    float* out = (float*)d_out;

    float* ws = (float*)d_ws;
    const int PER = RN * DD;               // 196608
    float* qb = ws;                        // PER f32
    __bf16* bfb  = (__bf16*)(ws + PER);
    __bf16* Arb  = bfb;                    // PER bf16 (row-major, k2a Apr)
    __bf16* Arv  = bfb + PER;              // PER bf16 (row-major, k2b Apv)
    __bf16* Abf  = bfb + 2 * PER;          // PER bf16 (frag-major)
    __bf16* Kbf  = bfb + 3 * PER;          // PER bf16 (frag-major)
    __bf16* Avf  = bfb + 4 * PER;          // PER bf16 (frag-major)
    __bf16* Vf   = bfb + 5 * (size_t)PER;  // PER bf16 (frag-major)
    __bf16* eG   = bfb + 6 * (size_t)PER;  // RN*HH*NN bf16
    float* Zpart = (float*)(eG + (size_t)RN * HH * NN);   // RN*2*HH f32
    float* basef = Zpart + (size_t)RN * 2 * HH;           // PER f32
    float* rcpart = basef + PER;                          // 2*PER f32
    __bf16* w2neg = (__bf16*)(rcpart + 2 * (size_t)PER);  // 2048 bf16

    prep_kernel<<<1345, 256, 0, stream>>>(x, coords, qkv_w, qkv_b,
                                          rb_w1, rv_w1, rb_w2,
                                          qb, Arb, Arv, Abf, Kbf, Avf, Vf, w2neg);
    k2a_kernel<<<RN, 256, 0, stream>>>(rb_b1, w2neg, rb_b2,
                                       qb, Kbf, Abf, Arb, eG, Zpart);
    k2b_kernel<<<RN, 256, 0, stream>>>(rv_b1, rv_w2,
                                       Avf, Vf, Arv, eG, rcpart, basef);
    k2c_kernel<<<RN, 256, 0, stream>>>(rcpart, basef, Zpart, rv_b2, out);
}